// Round 5
// baseline (186.269 us; speedup 1.0000x reference)
//
#include <hip/hip_runtime.h>
#include <math.h>

#define Bb 256
#define Tt 256
#define Ee 384
#define Hh 64

typedef __attribute__((ext_vector_type(8))) short bf16x8;
typedef __attribute__((ext_vector_type(4))) float f32x4;

__device__ inline short f2bf(float f) {
    unsigned u = __float_as_uint(f);
    u += 0x7FFFu + ((u >> 16) & 1);      // RNE
    return (short)(u >> 16);
}
__device__ inline float bf2f(short s) {
    return __uint_as_float(((unsigned)(unsigned short)s) << 16);
}

#define MFMA16(a, b, c) __builtin_amdgcn_mfma_f32_16x16x32_bf16((a), (b), (c), 0, 0, 0)

// ---- W fragment buffer in d_ws: hi at 0, lo at 147456; frag (ec*12+tct)*1024 ----
#define WLO_OFF 147456

// ---- LDS byte offsets ----
// phase 1: double-buffered A staging, buf p at p*32768 (hi) / p*32768+16384 (lo)
// phase 2 (live after phase 1): same layout as R4
#define K_HI 0
#define K_LO 32768
#define VF   65536
#define QH   98304
#define QL   116736
#define PBASE 98304
#define SMEM_BYTES 135168

// ============ prep kernel: W -> bf16 hi/lo in B-fragment layout ============
__global__ __launch_bounds__(256) void prep_w(
    const float* __restrict__ Wq, const float* __restrict__ Wk,
    const float* __restrict__ Wv, unsigned char* __restrict__ wsp)
{
    int u = blockIdx.x * 256 + threadIdx.x;    // unit id, 9216 total
    if (u >= 9216) return;
    int frag = u >> 6;                          // ec*12 + tct
    int lu   = u & 63;
    int ec   = frag / 12, tct = frag - ec * 12;
    int koct = lu >> 4, n = lu & 15;
    int col  = tct * 16 + n;
    const float* Wm = (col < 64) ? Wq : ((col < 128) ? Wk : Wv);
    int c = col & 63;
    bf16x8 hi8, lo8;
    #pragma unroll
    for (int j = 0; j < 8; ++j) {
        float v = Wm[(ec * 32 + koct * 8 + j) * 64 + c];
        short h = f2bf(v);
        hi8[j] = h;
        lo8[j] = f2bf(v - bf2f(h));
    }
    *reinterpret_cast<bf16x8*>(wsp + frag * 1024 + lu * 16) = hi8;
    *reinterpret_cast<bf16x8*>(wsp + WLO_OFF + frag * 1024 + lu * 16) = lo8;
}

// ============ main fused kernel ============
__global__ __launch_bounds__(1024) void head_fused(
    const float* __restrict__ x,
    const float* __restrict__ bq, const float* __restrict__ bk,
    const float* __restrict__ bv,
    const unsigned char* __restrict__ wsp,
    float* __restrict__ out)
{
    __shared__ __align__(16) unsigned char smem[SMEM_BYTES];

    const int b    = blockIdx.x;
    const int tid  = threadIdx.x;
    const int w    = tid >> 6;        // wave 0..15
    const int lane = tid & 63;
    const int quad = lane >> 4;
    const int nl   = lane & 15;
    const int ri   = w >> 2;          // rowtile group: rowtiles 4ri..4ri+3 (rows 64ri..64ri+63)
    const int cj   = w & 3;           // coltile group: tiles 3cj..3cj+2 (cols 48cj..48cj+47)

    f32x4 acc[4][3];
    #pragma unroll
    for (int i = 0; i < 4; ++i)
        #pragma unroll
        for (int j = 0; j < 3; ++j) acc[i][j] = (f32x4){0,0,0,0};

    const float4* x4 = reinterpret_cast<const float4*>(x + (size_t)b * Tt * Ee);

    // A staging map: dest unit tid -> rowtile tid>>6, koct=(tid>>4)&3, row=tid&15
    const int At  = ((tid >> 6) << 4) + (tid & 15);
    const int Ako = (tid >> 4) & 3;
    const float4* xsrc = x4 + At * 96 + Ako * 2;

    // convert+write chunk 0 -> buf0
    float4 pa0 = xsrc[0], pa1 = xsrc[1];
    {
        float v[8] = {pa0.x, pa0.y, pa0.z, pa0.w, pa1.x, pa1.y, pa1.z, pa1.w};
        bf16x8 hi8, lo8;
        #pragma unroll
        for (int j = 0; j < 8; ++j) {
            short h = f2bf(v[j]);
            hi8[j] = h;
            lo8[j] = f2bf(v[j] - bf2f(h));
        }
        *reinterpret_cast<bf16x8*>(smem + tid * 16) = hi8;
        *reinterpret_cast<bf16x8*>(smem + 16384 + tid * 16) = lo8;
    }
    pa0 = xsrc[8]; pa1 = xsrc[9];    // prefetch chunk 1

    // ================= Phase 1: one barrier per ec, A dbuf, B from global =================
    for (int ec = 0; ec < 12; ++ec) {
        __syncthreads();
        const int bufr = (ec & 1) * 32768;
        // B-frag loads (L2-resident, 1KB contiguous per wave)
        bf16x8 bh[3], bl[3];
        #pragma unroll
        for (int ct = 0; ct < 3; ++ct) {
            size_t o = (size_t)(ec * 12 + cj * 3 + ct) * 1024 + lane * 16;
            bh[ct] = *reinterpret_cast<const bf16x8*>(wsp + o);
            bl[ct] = *reinterpret_cast<const bf16x8*>(wsp + WLO_OFF + o);
        }
        // convert + write NEXT chunk into other buffer (overlaps MFMA below)
        if (ec < 11) {
            float v[8] = {pa0.x, pa0.y, pa0.z, pa0.w, pa1.x, pa1.y, pa1.z, pa1.w};
            bf16x8 hi8, lo8;
            #pragma unroll
            for (int j = 0; j < 8; ++j) {
                short h = f2bf(v[j]);
                hi8[j] = h;
                lo8[j] = f2bf(v[j] - bf2f(h));
            }
            int nb = (1 - (ec & 1)) * 32768;
            *reinterpret_cast<bf16x8*>(smem + nb + tid * 16) = hi8;
            *reinterpret_cast<bf16x8*>(smem + nb + 16384 + tid * 16) = lo8;
        }
        if (ec < 10) { pa0 = xsrc[(ec + 2) * 8]; pa1 = xsrc[(ec + 2) * 8 + 1]; }

        // MFMA: 4 rowtiles x 3 coltiles, hi/lo 3-term split
        #pragma unroll
        for (int rt = 0; rt < 4; ++rt) {
            int ao = bufr + (4 * ri + rt) * 1024 + lane * 16;
            bf16x8 ah = *reinterpret_cast<bf16x8*>(smem + ao);
            bf16x8 al = *reinterpret_cast<bf16x8*>(smem + ao + 16384);
            #pragma unroll
            for (int ct = 0; ct < 3; ++ct) {
                acc[rt][ct] = MFMA16(ah, bh[ct], acc[rt][ct]);
                acc[rt][ct] = MFMA16(al, bh[ct], acc[rt][ct]);
                acc[rt][ct] = MFMA16(ah, bl[ct], acc[rt][ct]);
            }
        }
    }
    __syncthreads();   // staging dead; phase-2 regions go live

    // ---- fold biases ----
    #pragma unroll
    for (int ct = 0; ct < 3; ++ct) {
        int col = (cj * 3 + ct) * 16 + nl;
        float bias = (col < 64) ? bq[col] : (col < 128 ? bk[col - 64] : bv[col - 128]);
        #pragma unroll
        for (int rt = 0; rt < 4; ++rt)
            #pragma unroll
            for (int r = 0; r < 4; ++r) acc[rt][ct][r] += bias;
    }

    // ---- scatter K (hi/lo) and V (bf16) into B-frag layout ----
    #pragma unroll
    for (int ct = 0; ct < 3; ++ct) {
        int col = (cj * 3 + ct) * 16 + nl;
        #pragma unroll
        for (int rt = 0; rt < 4; ++rt) {
            #pragma unroll
            for (int r = 0; r < 4; ++r) {
                float val = acc[rt][ct][r];
                int s = ri * 64 + rt * 16 + quad * 4 + r;
                if (col >= 64 && col < 128) {
                    int h = col - 64;
                    int addr = ((s >> 4) * 2 + (h >> 5)) * 1024
                             + ((((h & 31) >> 3) * 16 + (s & 15)) * 8 + (h & 7)) * 2;
                    short hi = f2bf(val);
                    short lo = f2bf(val - bf2f(hi));
                    *reinterpret_cast<short*>(smem + K_HI + addr) = hi;
                    *reinterpret_cast<short*>(smem + K_LO + addr) = lo;
                } else if (col >= 128) {
                    int h = col - 128, sl = s & 31;
                    int addr = ((s >> 5) * 4 + (h >> 4)) * 1024
                             + (((sl >> 3) * 16 + (h & 15)) * 8 + (sl & 7)) * 2;
                    *reinterpret_cast<short*>(smem + VF + addr) = f2bf(val);
                }
            }
        }
    }

    // ---- Q round-trip through LDS, two half-phases ----
    auto writeQhalf = [&](int half) {
        #pragma unroll
        for (int ct = 0; ct < 3; ++ct) {
            int col = (cj * 3 + ct) * 16 + nl;
            if (col < 64) {
                #pragma unroll
                for (int rt = 0; rt < 4; ++rt) {
                    #pragma unroll
                    for (int r = 0; r < 4; ++r) {
                        float val = acc[rt][ct][r];
                        int s = ri * 64 + rt * 16 + quad * 4 + r;
                        int rloc = s & 127;
                        short hi = f2bf(val);
                        short lo = f2bf(val - bf2f(hi));
                        *reinterpret_cast<short*>(smem + QH + (rloc * 72 + col) * 2) = hi;
                        *reinterpret_cast<short*>(smem + QL + (rloc * 72 + col) * 2) = lo;
                    }
                }
            }
        }
    };
    bf16x8 qh0, qh1, ql0, ql1;
    auto readQ = [&]() {
        int rloc = (16 * w + nl) & 127;
        int base = rloc * 144;
        qh0 = *reinterpret_cast<bf16x8*>(smem + QH + base + quad * 16);
        qh1 = *reinterpret_cast<bf16x8*>(smem + QH + base + 64 + quad * 16);
        ql0 = *reinterpret_cast<bf16x8*>(smem + QL + base + quad * 16);
        ql1 = *reinterpret_cast<bf16x8*>(smem + QL + base + 64 + quad * 16);
    };

    if (ri < 2) writeQhalf(0);       // rows 0..127 (only Q-col owners write inside)
    __syncthreads();
    if (w < 8) readQ();
    __syncthreads();
    if (ri >= 2) writeQhalf(1);      // rows 128..255
    __syncthreads();
    if (w >= 8) readQ();
    __syncthreads();

    // ================= Phase 2: causal attention, wave w owns rows 16w..16w+15 =================
    f32x4 oacc[4];
    #pragma unroll
    for (int i = 0; i < 4; ++i) oacc[i] = (f32x4){0,0,0,0};
    float lsum = 0.f;
    const int t0 = w * 16;
    unsigned char* pb = smem + PBASE + w * 1344;
    const int npairs = (w >> 1) + 1;

    for (int p = 0; p < npairs; ++p) {
        #pragma unroll
        for (int hf = 0; hf < 2; ++hf) {
            int st = 2 * p + hf;
            f32x4 s0 = (f32x4){0,0,0,0}, s1 = (f32x4){0,0,0,0};
            int kb = st * 2048 + lane * 16;
            bf16x8 kh0 = *reinterpret_cast<bf16x8*>(smem + K_HI + kb);
            bf16x8 kh1 = *reinterpret_cast<bf16x8*>(smem + K_HI + kb + 1024);
            bf16x8 kl0 = *reinterpret_cast<bf16x8*>(smem + K_LO + kb);
            bf16x8 kl1 = *reinterpret_cast<bf16x8*>(smem + K_LO + kb + 1024);
            s0 = MFMA16(qh0, kh0, s0);
            s1 = MFMA16(qh1, kh1, s1);
            s0 = MFMA16(ql0, kh0, s0);
            s1 = MFMA16(ql1, kh1, s1);
            s0 = MFMA16(qh0, kl0, s0);
            s1 = MFMA16(qh1, kl1, s1);
            int sg = st * 16 + nl;
            #pragma unroll
            for (int r = 0; r < 4; ++r) {
                int tg = t0 + quad * 4 + r;
                float sv = s0[r] + s1[r];
                float pv = (sg <= tg) ? __expf(sv) : 0.f;
                *reinterpret_cast<short*>(pb + ((quad * 4 + r) * 40 + hf * 16 + nl) * 2) = f2bf(pv);
            }
        }
        asm volatile("s_waitcnt lgkmcnt(0)" ::: "memory");
        bf16x8 pa = *reinterpret_cast<bf16x8*>(pb + (nl * 40 + quad * 8) * 2);
        float ls = 0.f;
        #pragma unroll
        for (int j = 0; j < 8; ++j) ls += bf2f(pa[j]);
        ls += __shfl_xor(ls, 16);
        ls += __shfl_xor(ls, 32);
        lsum += ls;
        int vb = p * 4096 + lane * 16;
        #pragma unroll
        for (int nt = 0; nt < 4; ++nt) {
            bf16x8 vf = *reinterpret_cast<bf16x8*>(smem + VF + vb + nt * 1024);
            oacc[nt] = MFMA16(pa, vf, oacc[nt]);
        }
    }

    // ---- normalize + write out ----
    float* lb_ = reinterpret_cast<float*>(pb + 1280);
    if (lane < 16) lb_[lane] = lsum;
    asm volatile("s_waitcnt lgkmcnt(0)" ::: "memory");
    float* ob = out + (size_t)b * Tt * Hh + (size_t)t0 * Hh;
    #pragma unroll
    for (int r = 0; r < 4; ++r) {
        float inv = 1.0f / lb_[quad * 4 + r];
        #pragma unroll
        for (int nt = 0; nt < 4; ++nt)
            ob[(quad * 4 + r) * 64 + nt * 16 + nl] = oacc[nt][r] * inv;
    }
}

extern "C" void kernel_launch(void* const* d_in, const int* in_sizes, int n_in,
                              void* d_out, int out_size, void* d_ws, size_t ws_size,
                              hipStream_t stream) {
    const float* x  = (const float*)d_in[0];
    const float* Wq = (const float*)d_in[1];
    const float* bq = (const float*)d_in[2];
    const float* Wk = (const float*)d_in[3];
    const float* bk = (const float*)d_in[4];
    const float* Wv = (const float*)d_in[5];
    const float* bv = (const float*)d_in[6];
    float* out = (float*)d_out;
    unsigned char* wsp = (unsigned char*)d_ws;   // needs 294912 B
    hipLaunchKernelGGL(prep_w, dim3(36), dim3(256), 0, stream, Wq, Wk, Wv, wsp);
    hipLaunchKernelGGL(head_fused, dim3(Bb), dim3(1024), 0, stream,
                       x, bq, bk, bv, wsp, out);
}

// Round 6
// 182.827 us; speedup vs baseline: 1.0188x; 1.0188x over previous
//
#include <hip/hip_runtime.h>
#include <math.h>

#define Bb 256
#define Tt 256
#define Ee 384
#define Hh 64

typedef __attribute__((ext_vector_type(8))) short bf16x8;
typedef __attribute__((ext_vector_type(4))) float f32x4;

__device__ inline short f2bf(float f) {
    unsigned u = __float_as_uint(f);
    u += 0x7FFFu + ((u >> 16) & 1);      // RNE
    return (short)(u >> 16);
}
__device__ inline float bf2f(short s) {
    return __uint_as_float(((unsigned)(unsigned short)s) << 16);
}

#define MFMA16(a, b, c) __builtin_amdgcn_mfma_f32_16x16x32_bf16((a), (b), (c), 0, 0, 0)

// ---- W fragment buffer in d_ws: hi at 0, lo at 147456; frag (ec*12+tct)*1024 ----
#define WLO_OFF 147456

// ---- LDS byte offsets ----
// phase 1: A dbuf at p*32768 (hi) / +16384 (lo); B dbuf at 65536 + p*24576 (hi) / +12288 (lo)
#define BB0 65536
// phase 2 (live after phase 1):
#define K_HI 0
#define K_LO 32768
#define VF   65536
#define QH   98304
#define QL   116736
#define PBASE 98304
#define SMEM_BYTES 135168

// ============ prep kernel: W -> bf16 hi/lo in B-fragment layout ============
__global__ __launch_bounds__(256) void prep_w(
    const float* __restrict__ Wq, const float* __restrict__ Wk,
    const float* __restrict__ Wv, unsigned char* __restrict__ wsp)
{
    int u = blockIdx.x * 256 + threadIdx.x;    // unit id, 9216 total
    if (u >= 9216) return;
    int frag = u >> 6;                          // ec*12 + tct
    int lu   = u & 63;
    int ec   = frag / 12, tct = frag - ec * 12;
    int koct = lu >> 4, n = lu & 15;
    int col  = tct * 16 + n;
    const float* Wm = (col < 64) ? Wq : ((col < 128) ? Wk : Wv);
    int c = col & 63;
    bf16x8 hi8, lo8;
    #pragma unroll
    for (int j = 0; j < 8; ++j) {
        float v = Wm[(ec * 32 + koct * 8 + j) * 64 + c];
        short h = f2bf(v);
        hi8[j] = h;
        lo8[j] = f2bf(v - bf2f(h));
    }
    *reinterpret_cast<bf16x8*>(wsp + frag * 1024 + lu * 16) = hi8;
    *reinterpret_cast<bf16x8*>(wsp + WLO_OFF + frag * 1024 + lu * 16) = lo8;
}

// ============ main fused kernel ============
__global__ __launch_bounds__(1024) void head_fused(
    const float* __restrict__ x,
    const float* __restrict__ bq, const float* __restrict__ bk,
    const float* __restrict__ bv,
    const unsigned char* __restrict__ wsp,
    float* __restrict__ out)
{
    __shared__ __align__(16) unsigned char smem[SMEM_BYTES];

    const int b    = blockIdx.x;
    const int tid  = threadIdx.x;
    const int w    = tid >> 6;        // wave 0..15
    const int lane = tid & 63;
    const int quad = lane >> 4;
    const int nl   = lane & 15;
    const int ri   = w >> 2;          // rowtiles 4ri..4ri+3 (rows 64ri..64ri+63)
    const int cj   = w & 3;           // coltiles 3cj..3cj+2

    f32x4 acc[4][3];
    #pragma unroll
    for (int i = 0; i < 4; ++i)
        #pragma unroll
        for (int j = 0; j < 3; ++j) acc[i][j] = (f32x4){0,0,0,0};

    const float4* x4 = reinterpret_cast<const float4*>(x + (size_t)b * Tt * Ee);

    // A staging map: dest unit tid -> rowtile tid>>6, koct=(tid>>4)&3, row=tid&15
    const int At  = ((tid >> 6) << 4) + (tid & 15);
    const int Ako = (tid >> 4) & 3;
    const float4* xsrc = x4 + At * 96 + Ako * 2;

    // B-frag DMA: once per CU per ec; waves 0..11 move 1 hi + 1 lo frag each.
    // LDS dest is wave-uniform base; HW scatters lane i at base + i*16 (m97 pattern).
    auto bgld = [&](int ecn) {
        if (w < 12) {
            int p = ecn & 1;
            const unsigned char* ghi = wsp + (size_t)(ecn * 12 + w) * 1024 + (size_t)lane * 16;
            const unsigned char* glo = ghi + WLO_OFF;
            __builtin_amdgcn_global_load_lds(
                (const __attribute__((address_space(1))) unsigned*)ghi,
                (__attribute__((address_space(3))) unsigned*)(smem + BB0 + p * 24576 + w * 1024),
                16, 0, 0);
            __builtin_amdgcn_global_load_lds(
                (const __attribute__((address_space(1))) unsigned*)glo,
                (__attribute__((address_space(3))) unsigned*)(smem + BB0 + p * 24576 + 12288 + w * 1024),
                16, 0, 0);
        }
    };

    // ---- preloop: B(0) DMA + A(0) staged + x(1) prefetched ----
    bgld(0);
    float4 pa0 = xsrc[0], pa1 = xsrc[1];
    {
        float v[8] = {pa0.x, pa0.y, pa0.z, pa0.w, pa1.x, pa1.y, pa1.z, pa1.w};
        bf16x8 hi8, lo8;
        #pragma unroll
        for (int j = 0; j < 8; ++j) {
            short h = f2bf(v[j]);
            hi8[j] = h;
            lo8[j] = f2bf(v[j] - bf2f(h));
        }
        *reinterpret_cast<bf16x8*>(smem + tid * 16) = hi8;
        *reinterpret_cast<bf16x8*>(smem + 16384 + tid * 16) = lo8;
    }
    pa0 = xsrc[8]; pa1 = xsrc[9];

    // ================= Phase 1: one barrier per ec, A+B double-buffered =================
    for (int ec = 0; ec < 12; ++ec) {
        __syncthreads();   // drains B-DMA(ec) + x loads(ec+1); staging(ec) visible
        // earliest issue: next iteration's B-frag DMA (full iter to complete)
        if (ec < 11) bgld(ec + 1);
        // stage A(ec+1) from prefetched regs into the other buffer
        if (ec < 11) {
            float v[8] = {pa0.x, pa0.y, pa0.z, pa0.w, pa1.x, pa1.y, pa1.z, pa1.w};
            bf16x8 hi8, lo8;
            #pragma unroll
            for (int j = 0; j < 8; ++j) {
                short h = f2bf(v[j]);
                hi8[j] = h;
                lo8[j] = f2bf(v[j] - bf2f(h));
            }
            int nb = (1 - (ec & 1)) * 32768;
            *reinterpret_cast<bf16x8*>(smem + nb + tid * 16) = hi8;
            *reinterpret_cast<bf16x8*>(smem + nb + 16384 + tid * 16) = lo8;
        }
        if (ec < 10) { pa0 = xsrc[(ec + 2) * 8]; pa1 = xsrc[(ec + 2) * 8 + 1]; }

        // MFMA over buffers (ec & 1): A 4 rowtiles x B 3 coltiles, hi/lo 3-term split
        const int ab = (ec & 1) * 32768;
        const int bb = BB0 + (ec & 1) * 24576;
        bf16x8 bh[3], bl[3];
        #pragma unroll
        for (int ct = 0; ct < 3; ++ct) {
            int o = bb + (cj * 3 + ct) * 1024 + lane * 16;
            bh[ct] = *reinterpret_cast<bf16x8*>(smem + o);
            bl[ct] = *reinterpret_cast<bf16x8*>(smem + o + 12288);
        }
        #pragma unroll
        for (int rt = 0; rt < 4; ++rt) {
            int ao = ab + (4 * ri + rt) * 1024 + lane * 16;
            bf16x8 ah = *reinterpret_cast<bf16x8*>(smem + ao);
            bf16x8 al = *reinterpret_cast<bf16x8*>(smem + ao + 16384);
            #pragma unroll
            for (int ct = 0; ct < 3; ++ct) {
                acc[rt][ct] = MFMA16(ah, bh[ct], acc[rt][ct]);
                acc[rt][ct] = MFMA16(al, bh[ct], acc[rt][ct]);
                acc[rt][ct] = MFMA16(ah, bl[ct], acc[rt][ct]);
            }
        }
    }
    __syncthreads();   // staging dead; phase-2 regions go live

    // ---- fold biases ----
    #pragma unroll
    for (int ct = 0; ct < 3; ++ct) {
        int col = (cj * 3 + ct) * 16 + nl;
        float bias = (col < 64) ? bq[col] : (col < 128 ? bk[col - 64] : bv[col - 128]);
        #pragma unroll
        for (int rt = 0; rt < 4; ++rt)
            #pragma unroll
            for (int r = 0; r < 4; ++r) acc[rt][ct][r] += bias;
    }

    // ---- scatter K (hi/lo) and V (bf16) into B-frag layout ----
    #pragma unroll
    for (int ct = 0; ct < 3; ++ct) {
        int col = (cj * 3 + ct) * 16 + nl;
        #pragma unroll
        for (int rt = 0; rt < 4; ++rt) {
            #pragma unroll
            for (int r = 0; r < 4; ++r) {
                float val = acc[rt][ct][r];
                int s = ri * 64 + rt * 16 + quad * 4 + r;
                if (col >= 64 && col < 128) {
                    int h = col - 64;
                    int addr = ((s >> 4) * 2 + (h >> 5)) * 1024
                             + ((((h & 31) >> 3) * 16 + (s & 15)) * 8 + (h & 7)) * 2;
                    short hi = f2bf(val);
                    short lo = f2bf(val - bf2f(hi));
                    *reinterpret_cast<short*>(smem + K_HI + addr) = hi;
                    *reinterpret_cast<short*>(smem + K_LO + addr) = lo;
                } else if (col >= 128) {
                    int h = col - 128, sl = s & 31;
                    int addr = ((s >> 5) * 4 + (h >> 4)) * 1024
                             + (((sl >> 3) * 16 + (h & 15)) * 8 + (sl & 7)) * 2;
                    *reinterpret_cast<short*>(smem + VF + addr) = f2bf(val);
                }
            }
        }
    }

    // ---- Q round-trip through LDS, two half-phases ----
    auto writeQhalf = [&]() {
        #pragma unroll
        for (int ct = 0; ct < 3; ++ct) {
            int col = (cj * 3 + ct) * 16 + nl;
            if (col < 64) {
                #pragma unroll
                for (int rt = 0; rt < 4; ++rt) {
                    #pragma unroll
                    for (int r = 0; r < 4; ++r) {
                        float val = acc[rt][ct][r];
                        int s = ri * 64 + rt * 16 + quad * 4 + r;
                        int rloc = s & 127;
                        short hi = f2bf(val);
                        short lo = f2bf(val - bf2f(hi));
                        *reinterpret_cast<short*>(smem + QH + (rloc * 72 + col) * 2) = hi;
                        *reinterpret_cast<short*>(smem + QL + (rloc * 72 + col) * 2) = lo;
                    }
                }
            }
        }
    };
    bf16x8 qh0, qh1, ql0, ql1;
    auto readQ = [&]() {
        int rloc = (16 * w + nl) & 127;
        int base = rloc * 144;
        qh0 = *reinterpret_cast<bf16x8*>(smem + QH + base + quad * 16);
        qh1 = *reinterpret_cast<bf16x8*>(smem + QH + base + 64 + quad * 16);
        ql0 = *reinterpret_cast<bf16x8*>(smem + QL + base + quad * 16);
        ql1 = *reinterpret_cast<bf16x8*>(smem + QL + base + 64 + quad * 16);
    };

    if (ri < 2) writeQhalf();        // rows 0..127
    __syncthreads();
    if (w < 8) readQ();
    __syncthreads();
    if (ri >= 2) writeQhalf();       // rows 128..255
    __syncthreads();
    if (w >= 8) readQ();
    __syncthreads();

    // ================= Phase 2: causal attention, wave w owns rows 16w..16w+15 =================
    f32x4 oacc[4];
    #pragma unroll
    for (int i = 0; i < 4; ++i) oacc[i] = (f32x4){0,0,0,0};
    float lsum = 0.f;
    const int t0 = w * 16;
    unsigned char* pb = smem + PBASE + w * 1344;
    const int npairs = (w >> 1) + 1;

    for (int p = 0; p < npairs; ++p) {
        #pragma unroll
        for (int hf = 0; hf < 2; ++hf) {
            int st = 2 * p + hf;
            f32x4 s0 = (f32x4){0,0,0,0}, s1 = (f32x4){0,0,0,0};
            int kb = st * 2048 + lane * 16;
            bf16x8 kh0 = *reinterpret_cast<bf16x8*>(smem + K_HI + kb);
            bf16x8 kh1 = *reinterpret_cast<bf16x8*>(smem + K_HI + kb + 1024);
            bf16x8 kl0 = *reinterpret_cast<bf16x8*>(smem + K_LO + kb);
            bf16x8 kl1 = *reinterpret_cast<bf16x8*>(smem + K_LO + kb + 1024);
            s0 = MFMA16(qh0, kh0, s0);
            s1 = MFMA16(qh1, kh1, s1);
            s0 = MFMA16(ql0, kh0, s0);
            s1 = MFMA16(ql1, kh1, s1);
            s0 = MFMA16(qh0, kl0, s0);
            s1 = MFMA16(qh1, kl1, s1);
            int sg = st * 16 + nl;
            #pragma unroll
            for (int r = 0; r < 4; ++r) {
                int tg = t0 + quad * 4 + r;
                float sv = s0[r] + s1[r];
                float pv = (sg <= tg) ? __expf(sv) : 0.f;
                *reinterpret_cast<short*>(pb + ((quad * 4 + r) * 40 + hf * 16 + nl) * 2) = f2bf(pv);
            }
        }
        asm volatile("s_waitcnt lgkmcnt(0)" ::: "memory");
        bf16x8 pa = *reinterpret_cast<bf16x8*>(pb + (nl * 40 + quad * 8) * 2);
        float ls = 0.f;
        #pragma unroll
        for (int j = 0; j < 8; ++j) ls += bf2f(pa[j]);
        ls += __shfl_xor(ls, 16);
        ls += __shfl_xor(ls, 32);
        lsum += ls;
        int vb = p * 4096 + lane * 16;
        #pragma unroll
        for (int nt = 0; nt < 4; ++nt) {
            bf16x8 vf = *reinterpret_cast<bf16x8*>(smem + VF + vb + nt * 1024);
            oacc[nt] = MFMA16(pa, vf, oacc[nt]);
        }
    }

    // ---- normalize + write out ----
    float* lb_ = reinterpret_cast<float*>(pb + 1280);
    if (lane < 16) lb_[lane] = lsum;
    asm volatile("s_waitcnt lgkmcnt(0)" ::: "memory");
    float* ob = out + (size_t)b * Tt * Hh + (size_t)t0 * Hh;
    #pragma unroll
    for (int r = 0; r < 4; ++r) {
        float inv = 1.0f / lb_[quad * 4 + r];
        #pragma unroll
        for (int nt = 0; nt < 4; ++nt)
            ob[(quad * 4 + r) * 64 + nt * 16 + nl] = oacc[nt][r] * inv;
    }
}

extern "C" void kernel_launch(void* const* d_in, const int* in_sizes, int n_in,
                              void* d_out, int out_size, void* d_ws, size_t ws_size,
                              hipStream_t stream) {
    const float* x  = (const float*)d_in[0];
    const float* Wq = (const float*)d_in[1];
    const float* bq = (const float*)d_in[2];
    const float* Wk = (const float*)d_in[3];
    const float* bk = (const float*)d_in[4];
    const float* Wv = (const float*)d_in[5];
    const float* bv = (const float*)d_in[6];
    float* out = (float*)d_out;
    unsigned char* wsp = (unsigned char*)d_ws;   // needs 294912 B
    hipLaunchKernelGGL(prep_w, dim3(36), dim3(256), 0, stream, Wq, Wk, Wv, wsp);
    hipLaunchKernelGGL(head_fused, dim3(Bb), dim3(1024), 0, stream,
                       x, bq, bk, bv, wsp, out);
}